// Round 1
// baseline (51.517 us; speedup 1.0000x reference)
//
#include <hip/hip_runtime.h>
#include <hip/hip_bf16.h>

#define N 512
#define D 256
#define MARGIN 0.1f
#define EPSF 1e-16f

// ---------------- Kernel 0: squared norms ----------------
__global__ __launch_bounds__(64) void sqn_kernel(const float* __restrict__ E,
                                                 float* __restrict__ sqn) {
    int i = blockIdx.x;
    int t = threadIdx.x;
    const float* row = E + i * D;
    float p = 0.0f;
    #pragma unroll
    for (int d = 0; d < D / 64; ++d) {
        float v = row[t + d * 64];
        p += v * v;
    }
    #pragma unroll
    for (int off = 32; off > 0; off >>= 1)
        p += __shfl_down(p, off);
    if (t == 0) sqn[i] = p;
}

// ---------------- Kernel 1: pairwise distances (32x32 tiles) ----------------
#define PAD 4
__global__ __launch_bounds__(256) void pd_kernel(const float* __restrict__ E,
                                                 const float* __restrict__ sqn,
                                                 float* __restrict__ pd) {
    __shared__ float As[32][D + PAD];
    __shared__ float Bs[32][D + PAD];
    int bi = blockIdx.y, bj = blockIdx.x;
    int t = threadIdx.x;

    const float4* E4 = (const float4*)E;  // row = 64 float4
    #pragma unroll
    for (int it = 0; it < 8; ++it) {
        int idx = it * 256 + t;     // 0..2047 float4 slots in a 32x256 tile
        int r = idx >> 6;
        int c = idx & 63;
        float4 va = E4[(bi * 32 + r) * 64 + c];
        *(float4*)&As[r][c * 4] = va;
        float4 vb = E4[(bj * 32 + r) * 64 + c];
        *(float4*)&Bs[r][c * 4] = vb;
    }
    __syncthreads();

    int ri = t >> 4;   // 0..15
    int cj = t & 15;   // 0..15
    float a00 = 0.f, a01 = 0.f, a10 = 0.f, a11 = 0.f;
    for (int d = 0; d < D; d += 4) {
        float4 x0 = *(const float4*)&As[ri][d];
        float4 x1 = *(const float4*)&As[ri + 16][d];
        float4 y0 = *(const float4*)&Bs[cj][d];
        float4 y1 = *(const float4*)&Bs[cj + 16][d];
        a00 += x0.x * y0.x + x0.y * y0.y + x0.z * y0.z + x0.w * y0.w;
        a01 += x0.x * y1.x + x0.y * y1.y + x0.z * y1.z + x0.w * y1.w;
        a10 += x1.x * y0.x + x1.y * y0.y + x1.z * y0.z + x1.w * y0.w;
        a11 += x1.x * y1.x + x1.y * y1.y + x1.z * y1.z + x1.w * y1.w;
    }

    int gi0 = bi * 32 + ri, gi1 = gi0 + 16;
    int gj0 = bj * 32 + cj, gj1 = gj0 + 16;
    float si0 = sqn[gi0], si1 = sqn[gi1];
    float sj0 = sqn[gj0], sj1 = sqn[gj1];

    {
        float dd = si0 - 2.0f * a00 + sj0;
        dd = fmaxf(dd, 0.0f);
        pd[gi0 * N + gj0] = (dd > 0.0f) ? sqrtf(dd) : 0.0f;
    }
    {
        float dd = si0 - 2.0f * a01 + sj1;
        dd = fmaxf(dd, 0.0f);
        pd[gi0 * N + gj1] = (dd > 0.0f) ? sqrtf(dd) : 0.0f;
    }
    {
        float dd = si1 - 2.0f * a10 + sj0;
        dd = fmaxf(dd, 0.0f);
        pd[gi1 * N + gj0] = (dd > 0.0f) ? sqrtf(dd) : 0.0f;
    }
    {
        float dd = si1 - 2.0f * a11 + sj1;
        dd = fmaxf(dd, 0.0f);
        pd[gi1 * N + gj1] = (dd > 0.0f) ? sqrtf(dd) : 0.0f;
    }
}

// ---------------- Kernel 2: per-anchor triplet accumulation ----------------
__global__ __launch_bounds__(256) void triplet_kernel(const float* __restrict__ pd,
                                                      const int* __restrict__ labels,
                                                      float* __restrict__ bsum,
                                                      float* __restrict__ bcnt) {
    __shared__ float row[N];
    __shared__ int   lab[N];
    __shared__ float ssum[256];
    __shared__ int   scnt[256];

    int i = blockIdx.x;
    int t = threadIdx.x;

    row[t]       = pd[i * N + t];
    row[t + 256] = pd[i * N + t + 256];
    lab[t]       = labels[t];
    lab[t + 256] = labels[t + 256];
    __syncthreads();

    int li = lab[i];
    int k1 = t, k2 = t + 256;
    bool n1 = (lab[k1] != li);
    bool n2 = (lab[k2] != li);
    float dn1 = row[k1];
    float dn2 = row[k2];

    float sum = 0.0f;
    int cnt = 0;
    for (int j = 0; j < N; ++j) {
        if (lab[j] != li || j == i) continue;   // wave-uniform branch
        float dap = row[j];
        float v1 = dap - dn1 + MARGIN;
        float v2 = dap - dn2 + MARGIN;
        if (n1 && v1 > 0.0f) { sum += v1; if (v1 > EPSF) cnt++; }
        if (n2 && v2 > 0.0f) { sum += v2; if (v2 > EPSF) cnt++; }
    }

    ssum[t] = sum;
    scnt[t] = cnt;
    __syncthreads();
    #pragma unroll
    for (int s = 128; s > 0; s >>= 1) {
        if (t < s) {
            ssum[t] += ssum[t + s];
            scnt[t] += scnt[t + s];
        }
        __syncthreads();
    }
    if (t == 0) {
        bsum[i] = ssum[0];
        bcnt[i] = (float)scnt[0];
    }
}

// ---------------- Kernel 3: final reduce ----------------
__global__ __launch_bounds__(256) void final_kernel(const float* __restrict__ bsum,
                                                    const float* __restrict__ bcnt,
                                                    float* __restrict__ out) {
    __shared__ double s[256];
    __shared__ double c[256];
    int t = threadIdx.x;
    s[t] = (double)bsum[t] + (double)bsum[t + 256];
    c[t] = (double)bcnt[t] + (double)bcnt[t + 256];
    __syncthreads();
    #pragma unroll
    for (int st = 128; st > 0; st >>= 1) {
        if (t < st) {
            s[t] += s[t + st];
            c[t] += c[t + st];
        }
        __syncthreads();
    }
    if (t == 0) {
        double cnt = c[0];
        out[0] = (float)(s[0] / (cnt + 1e-16));
        out[1] = (float)cnt;
    }
}

extern "C" void kernel_launch(void* const* d_in, const int* in_sizes, int n_in,
                              void* d_out, int out_size, void* d_ws, size_t ws_size,
                              hipStream_t stream) {
    const float* E      = (const float*)d_in[0];
    const int*   labels = (const int*)d_in[1];
    float* out = (float*)d_out;

    float* sqn  = (float*)d_ws;          // 512
    float* pd   = sqn + 512;             // 512*512
    float* bsum = pd + N * N;            // 512
    float* bcnt = bsum + 512;            // 512

    sqn_kernel<<<N, 64, 0, stream>>>(E, sqn);
    pd_kernel<<<dim3(16, 16), 256, 0, stream>>>(E, sqn, pd);
    triplet_kernel<<<N, 256, 0, stream>>>(pd, labels, bsum, bcnt);
    final_kernel<<<1, 256, 0, stream>>>(bsum, bcnt, out);
}

// Round 2
// 18.072 us; speedup vs baseline: 2.8507x; 2.8507x over previous
//
#include <hip/hip_runtime.h>
#include <hip/hip_bf16.h>

#define N 512
#define D 256
#define MARGIN 0.1f
#define EPSF 1e-16f

// ---------------- Kernel 1: pairwise distances (32x32 tiles) + fused norms ----------------
#define PAD 4
__global__ __launch_bounds__(256) void pd_kernel(const float* __restrict__ E,
                                                 float* __restrict__ pd) {
    __shared__ float As[32][D + PAD];
    __shared__ float Bs[32][D + PAD];
    __shared__ float norms[64];   // 0..31: As row norms, 32..63: Bs row norms
    int bi = blockIdx.y, bj = blockIdx.x;
    int t = threadIdx.x;

    const float4* E4 = (const float4*)E;  // row = 64 float4
    #pragma unroll
    for (int it = 0; it < 8; ++it) {
        int idx = it * 256 + t;     // 0..2047 float4 slots in a 32x256 tile
        int r = idx >> 6;
        int c = idx & 63;
        float4 va = E4[(bi * 32 + r) * 64 + c];
        *(float4*)&As[r][c * 4] = va;
        float4 vb = E4[(bj * 32 + r) * 64 + c];
        *(float4*)&Bs[r][c * 4] = vb;
    }
    __syncthreads();

    // fused squared-norms of the 64 staged rows: 4 threads per row, 64 dims each
    {
        int r  = t >> 2;          // 0..63
        int ch = t & 3;           // 0..3
        const float* src = (r < 32) ? &As[r][0] : &Bs[r - 32][0];
        float np = 0.0f;
        #pragma unroll
        for (int d = 0; d < 64; d += 4) {
            float4 x = *(const float4*)&src[ch * 64 + d];
            np += x.x * x.x + x.y * x.y + x.z * x.z + x.w * x.w;
        }
        np += __shfl_xor(np, 1);
        np += __shfl_xor(np, 2);
        if (ch == 0) norms[r] = np;
    }
    __syncthreads();

    int ri = t >> 4;   // 0..15
    int cj = t & 15;   // 0..15
    float a00 = 0.f, a01 = 0.f, a10 = 0.f, a11 = 0.f;
    for (int d = 0; d < D; d += 4) {
        float4 x0 = *(const float4*)&As[ri][d];
        float4 x1 = *(const float4*)&As[ri + 16][d];
        float4 y0 = *(const float4*)&Bs[cj][d];
        float4 y1 = *(const float4*)&Bs[cj + 16][d];
        a00 += x0.x * y0.x + x0.y * y0.y + x0.z * y0.z + x0.w * y0.w;
        a01 += x0.x * y1.x + x0.y * y1.y + x0.z * y1.z + x0.w * y1.w;
        a10 += x1.x * y0.x + x1.y * y0.y + x1.z * y0.z + x1.w * y0.w;
        a11 += x1.x * y1.x + x1.y * y1.y + x1.z * y1.z + x1.w * y1.w;
    }

    int gi0 = bi * 32 + ri, gi1 = gi0 + 16;
    int gj0 = bj * 32 + cj, gj1 = gj0 + 16;
    float si0 = norms[ri],      si1 = norms[ri + 16];
    float sj0 = norms[32 + cj], sj1 = norms[32 + cj + 16];

    {
        float dd = si0 - 2.0f * a00 + sj0;
        dd = fmaxf(dd, 0.0f);
        pd[gi0 * N + gj0] = (dd > 0.0f) ? sqrtf(dd) : 0.0f;
    }
    {
        float dd = si0 - 2.0f * a01 + sj1;
        dd = fmaxf(dd, 0.0f);
        pd[gi0 * N + gj1] = (dd > 0.0f) ? sqrtf(dd) : 0.0f;
    }
    {
        float dd = si1 - 2.0f * a10 + sj0;
        dd = fmaxf(dd, 0.0f);
        pd[gi1 * N + gj0] = (dd > 0.0f) ? sqrtf(dd) : 0.0f;
    }
    {
        float dd = si1 - 2.0f * a11 + sj1;
        dd = fmaxf(dd, 0.0f);
        pd[gi1 * N + gj1] = (dd > 0.0f) ? sqrtf(dd) : 0.0f;
    }
}

// ---------------- Kernel 2: per-anchor triplet accumulation (positive-compaction) ----------------
__global__ __launch_bounds__(256) void triplet_kernel(const float* __restrict__ pd,
                                                      const int* __restrict__ labels,
                                                      float* __restrict__ bsum,
                                                      float* __restrict__ bcnt) {
    __shared__ float row[N];
    __shared__ int   lab[N];
    __shared__ unsigned long long masks[8];
    __shared__ short plist[N];
    __shared__ float ssum[256];
    __shared__ int   scnt[256];

    int i = blockIdx.x;
    int t = threadIdx.x;
    int wave = t >> 6;      // 0..3
    int lane = t & 63;

    row[t]       = pd[i * N + t];
    row[t + 256] = pd[i * N + t + 256];
    lab[t]       = labels[t];
    lab[t + 256] = labels[t + 256];
    __syncthreads();

    int li = lab[i];
    int j1 = t, j2 = t + 256;     // j1 in chunk `wave`, j2 in chunk `wave+4`
    bool p1 = (lab[j1] == li) && (j1 != i);
    bool p2 = (lab[j2] == li) && (j2 != i);
    unsigned long long m1 = __ballot(p1);
    unsigned long long m2 = __ballot(p2);
    if (lane == 0) { masks[wave] = m1; masks[wave + 4] = m2; }
    __syncthreads();

    // deterministic prefix over chunks 0..7 (ascending j order)
    int base1 = 0, base2 = 0, npos = 0;
    #pragma unroll
    for (int c = 0; c < 8; ++c) {
        int pc = __popcll(masks[c]);
        if (c < wave)     base1 += pc;
        if (c < wave + 4) base2 += pc;
        npos += pc;
    }
    unsigned long long lower = (1ULL << lane) - 1ULL;
    if (p1) plist[base1 + __popcll(m1 & lower)] = (short)j1;
    if (p2) plist[base2 + __popcll(m2 & lower)] = (short)j2;
    __syncthreads();

    bool  n1  = (lab[j1] != li);
    bool  n2  = (lab[j2] != li);
    float dn1 = row[j1];
    float dn2 = row[j2];

    float sum = 0.0f;
    int cnt = 0;
    for (int p = 0; p < npos; ++p) {
        float dap = row[plist[p]];
        float v1 = dap - dn1 + MARGIN;
        float v2 = dap - dn2 + MARGIN;
        if (n1 && v1 > 0.0f) { sum += v1; cnt += (v1 > EPSF); }
        if (n2 && v2 > 0.0f) { sum += v2; cnt += (v2 > EPSF); }
    }

    ssum[t] = sum;
    scnt[t] = cnt;
    __syncthreads();
    #pragma unroll
    for (int s = 128; s > 0; s >>= 1) {
        if (t < s) {
            ssum[t] += ssum[t + s];
            scnt[t] += scnt[t + s];
        }
        __syncthreads();
    }
    if (t == 0) {
        bsum[i] = ssum[0];
        bcnt[i] = (float)scnt[0];
    }
}

// ---------------- Kernel 3: final reduce ----------------
__global__ __launch_bounds__(256) void final_kernel(const float* __restrict__ bsum,
                                                    const float* __restrict__ bcnt,
                                                    float* __restrict__ out) {
    __shared__ double s[256];
    __shared__ double c[256];
    int t = threadIdx.x;
    s[t] = (double)bsum[t] + (double)bsum[t + 256];
    c[t] = (double)bcnt[t] + (double)bcnt[t + 256];
    __syncthreads();
    #pragma unroll
    for (int st = 128; st > 0; st >>= 1) {
        if (t < st) {
            s[t] += s[t + st];
            c[t] += c[t + st];
        }
        __syncthreads();
    }
    if (t == 0) {
        double cnt = c[0];
        out[0] = (float)(s[0] / (cnt + 1e-16));
        out[1] = (float)cnt;
    }
}

extern "C" void kernel_launch(void* const* d_in, const int* in_sizes, int n_in,
                              void* d_out, int out_size, void* d_ws, size_t ws_size,
                              hipStream_t stream) {
    const float* E      = (const float*)d_in[0];
    const int*   labels = (const int*)d_in[1];
    float* out = (float*)d_out;

    float* pd   = (float*)d_ws;          // 512*512
    float* bsum = pd + N * N;            // 512
    float* bcnt = bsum + 512;            // 512

    pd_kernel<<<dim3(16, 16), 256, 0, stream>>>(E, pd);
    triplet_kernel<<<N, 256, 0, stream>>>(pd, labels, bsum, bcnt);
    final_kernel<<<1, 256, 0, stream>>>(bsum, bcnt, out);
}